// Round 1
// baseline (102.231 us; speedup 1.0000x reference)
//
#include <hip/hip_runtime.h>

#define NB 128
#define NS 65536

// In-wave 256-point Walsh-Hadamard transform (unnormalized).
// Element e = 4*lane + q. Bits 0,1 in registers; bits 2..7 via shfl_xor.
__device__ __forceinline__ void wht256(float (&xr)[4], float (&xi)[4], int lane) {
  {
    float t;
    t = xr[0]; xr[0] = t + xr[1]; xr[1] = t - xr[1];
    t = xr[2]; xr[2] = t + xr[3]; xr[3] = t - xr[3];
    t = xi[0]; xi[0] = t + xi[1]; xi[1] = t - xi[1];
    t = xi[2]; xi[2] = t + xi[3]; xi[3] = t - xi[3];
    t = xr[0]; xr[0] = t + xr[2]; xr[2] = t - xr[2];
    t = xr[1]; xr[1] = t + xr[3]; xr[3] = t - xr[3];
    t = xi[0]; xi[0] = t + xi[2]; xi[2] = t - xi[2];
    t = xi[1]; xi[1] = t + xi[3]; xi[3] = t - xi[3];
  }
#pragma unroll
  for (int m = 1; m <= 32; m <<= 1) {
    const bool up = (lane & m) != 0;
#pragma unroll
    for (int q = 0; q < 4; ++q) {
      float o = __shfl_xor(xr[q], m, 64);
      xr[q] = up ? (o - xr[q]) : (xr[q] + o);
      o = __shfl_xor(xi[q], m, 64);
      xi[q] = up ? (o - xi[q]) : (xi[q] + o);
    }
  }
}

// K1: WHT along lo byte; write transposed [b][lo][hi]; norm^2 partials.
__global__ __launch_bounds__(256) void k1_whtlo(const float* __restrict__ sre,
                                                const float* __restrict__ sim,
                                                float* __restrict__ Are,
                                                float* __restrict__ Aim,
                                                float* __restrict__ partial) {
  __shared__ float sr[16][260];
  __shared__ float si[16][260];
  __shared__ float red[4];
  const int bx = blockIdx.x;
  const int b = bx >> 4, tile = bx & 15;
  const int tid = threadIdx.x, lane = tid & 63, w = tid >> 6;
  const float* pre = sre + ((size_t)b << 16);
  const float* pim = sim + ((size_t)b << 16);
  float acc = 0.f;
#pragma unroll
  for (int r = 0; r < 4; ++r) {
    const int hl = w * 4 + r;
    const int hi = tile * 16 + hl;
    const float4 vr = *reinterpret_cast<const float4*>(pre + hi * 256 + lane * 4);
    const float4 vi = *reinterpret_cast<const float4*>(pim + hi * 256 + lane * 4);
    float xr[4] = {vr.x, vr.y, vr.z, vr.w};
    float xi[4] = {vi.x, vi.y, vi.z, vi.w};
    acc += xr[0]*xr[0]+xr[1]*xr[1]+xr[2]*xr[2]+xr[3]*xr[3]
         + xi[0]*xi[0]+xi[1]*xi[1]+xi[2]*xi[2]+xi[3]*xi[3];
    wht256(xr, xi, lane);
    *reinterpret_cast<float4*>(&sr[hl][lane * 4]) = make_float4(xr[0], xr[1], xr[2], xr[3]);
    *reinterpret_cast<float4*>(&si[hl][lane * 4]) = make_float4(xi[0], xi[1], xi[2], xi[3]);
  }
#pragma unroll
  for (int m = 32; m >= 1; m >>= 1) acc += __shfl_xor(acc, m, 64);
  if (lane == 0) red[w] = acc;
  __syncthreads();
  if (tid == 0) partial[bx] = red[0] + red[1] + red[2] + red[3];
  float* ore = Are + ((size_t)b << 16) + tile * 16;
  float* oim = Aim + ((size_t)b << 16) + tile * 16;
  const int q = tid & 3, l4 = tid >> 2;
#pragma unroll
  for (int it = 0; it < 4; ++it) {
    const int lo = it * 64 + l4;
    float4 o;
    o.x = sr[q*4+0][lo]; o.y = sr[q*4+1][lo]; o.z = sr[q*4+2][lo]; o.w = sr[q*4+3][lo];
    *reinterpret_cast<float4*>(ore + (size_t)lo * 256 + q * 4) = o;
    o.x = si[q*4+0][lo]; o.y = si[q*4+1][lo]; o.z = si[q*4+2][lo]; o.w = si[q*4+3][lo];
    *reinterpret_cast<float4*>(oim + (size_t)lo * 256 + q * 4) = o;
  }
}

// K2: WHT along hi byte + separable phase; write v natural [b][hi][lo].
__global__ __launch_bounds__(256) void k2_whthi_phase(const float* __restrict__ Are,
                                                      const float* __restrict__ Aim,
                                                      const float* __restrict__ thetas,
                                                      float* __restrict__ vre,
                                                      float* __restrict__ vim) {
  __shared__ float sr[16][260];
  __shared__ float si[16][260];
  __shared__ float2 phh[256];
  __shared__ float2 phl[16];
  __shared__ float th[16];
  const int bx = blockIdx.x;
  const int b = bx >> 4, tile = bx & 15;
  const int tid = threadIdx.x, lane = tid & 63, w = tid >> 6;
  if (tid < 16) th[tid] = thetas[b * 16 + tid];
  __syncthreads();
  {
    float ah = 0.f;
#pragma unroll
    for (int i = 0; i < 8; ++i)
      if ((tid >> (7 - i)) & 1) ah += th[i];
    phh[tid] = make_float2(cosf(0.5f * ah), -sinf(0.5f * ah));
    if (tid < 16) {
      const int lo = tile * 16 + tid;
      float al = 0.f;
#pragma unroll
      for (int i = 0; i < 8; ++i)
        if ((lo >> (7 - i)) & 1) al += th[8 + i];
      phl[tid] = make_float2(cosf(0.5f * al), -sinf(0.5f * al));
    }
  }
  __syncthreads();
  const float* pre = Are + ((size_t)b << 16);
  const float* pim = Aim + ((size_t)b << 16);
#pragma unroll
  for (int r = 0; r < 4; ++r) {
    const int ll = w * 4 + r;
    const int lo = tile * 16 + ll;
    const float4 vr = *reinterpret_cast<const float4*>(pre + lo * 256 + lane * 4);
    const float4 vi = *reinterpret_cast<const float4*>(pim + lo * 256 + lane * 4);
    float xr[4] = {vr.x, vr.y, vr.z, vr.w};
    float xi[4] = {vi.x, vi.y, vi.z, vi.w};
    wht256(xr, xi, lane);
    const float2 pl = phl[ll];
#pragma unroll
    for (int q = 0; q < 4; ++q) {
      const float2 ph = phh[lane * 4 + q];
      const float pr = pl.x * ph.x - pl.y * ph.y;
      const float pi = pl.x * ph.y + pl.y * ph.x;
      const float ur = xr[q], ui = xi[q];
      xr[q] = ur * pr - ui * pi;
      xi[q] = ur * pi + ui * pr;
    }
    *reinterpret_cast<float4*>(&sr[ll][lane * 4]) = make_float4(xr[0], xr[1], xr[2], xr[3]);
    *reinterpret_cast<float4*>(&si[ll][lane * 4]) = make_float4(xi[0], xi[1], xi[2], xi[3]);
  }
  __syncthreads();
  float* ore = vre + ((size_t)b << 16) + tile * 16;
  float* oim = vim + ((size_t)b << 16) + tile * 16;
  const int q = tid & 3, l4 = tid >> 2;
#pragma unroll
  for (int it = 0; it < 4; ++it) {
    const int hi = it * 64 + l4;
    float4 o;
    o.x = sr[q*4+0][hi]; o.y = sr[q*4+1][hi]; o.z = sr[q*4+2][hi]; o.w = sr[q*4+3][hi];
    *reinterpret_cast<float4*>(ore + (size_t)hi * 256 + q * 4) = o;
    o.x = si[q*4+0][hi]; o.y = si[q*4+1][hi]; o.z = si[q*4+2][hi]; o.w = si[q*4+3][hi];
    *reinterpret_cast<float4*>(oim + (size_t)hi * 256 + q * 4) = o;
  }
}

// K3: gather w[j]=v[cnot_p[j]] + WHT along lo; write transposed [b][lo][hi].
// blockIdx swizzled so each XCD works on a contiguous group of batch rows
// (gather working set per XCD stays L2-resident).
__global__ __launch_bounds__(256) void k3_gather_whtlo(const float* __restrict__ vre,
                                                       const float* __restrict__ vim,
                                                       const int* __restrict__ cnot,
                                                       float* __restrict__ Are,
                                                       float* __restrict__ Aim) {
  __shared__ float sr[16][260];
  __shared__ float si[16][260];
  const int bid = blockIdx.x;
  const int x = bid & 7, s = bid >> 3;
  const int b = x * 16 + (s >> 4), tile = s & 15;
  const int tid = threadIdx.x, lane = tid & 63, w = tid >> 6;
  const float* pre = vre + ((size_t)b << 16);
  const float* pim = vim + ((size_t)b << 16);
#pragma unroll
  for (int r = 0; r < 4; ++r) {
    const int hl = w * 4 + r;
    const int jhi = tile * 16 + hl;
    const int4 k4 = *reinterpret_cast<const int4*>(cnot + jhi * 256 + lane * 4);
    float xr[4], xi[4];
    xr[0] = pre[k4.x]; xi[0] = pim[k4.x];
    xr[1] = pre[k4.y]; xi[1] = pim[k4.y];
    xr[2] = pre[k4.z]; xi[2] = pim[k4.z];
    xr[3] = pre[k4.w]; xi[3] = pim[k4.w];
    wht256(xr, xi, lane);
    *reinterpret_cast<float4*>(&sr[hl][lane * 4]) = make_float4(xr[0], xr[1], xr[2], xr[3]);
    *reinterpret_cast<float4*>(&si[hl][lane * 4]) = make_float4(xi[0], xi[1], xi[2], xi[3]);
  }
  __syncthreads();
  float* ore = Are + ((size_t)b << 16) + tile * 16;
  float* oim = Aim + ((size_t)b << 16) + tile * 16;
  const int q = tid & 3, l4 = tid >> 2;
#pragma unroll
  for (int it = 0; it < 4; ++it) {
    const int lo = it * 64 + l4;
    float4 o;
    o.x = sr[q*4+0][lo]; o.y = sr[q*4+1][lo]; o.z = sr[q*4+2][lo]; o.w = sr[q*4+3][lo];
    *reinterpret_cast<float4*>(ore + (size_t)lo * 256 + q * 4) = o;
    o.x = si[q*4+0][lo]; o.y = si[q*4+1][lo]; o.z = si[q*4+2][lo]; o.w = si[q*4+3][lo];
    *reinterpret_cast<float4*>(oim + (size_t)lo * 256 + q * 4) = o;
  }
}

// K4: WHT along hi + |.|^2 * 1/(2^32 * norm2); write output natural layout.
__global__ __launch_bounds__(256) void k4_whthi_out(const float* __restrict__ Are,
                                                    const float* __restrict__ Aim,
                                                    const float* __restrict__ partial,
                                                    float* __restrict__ outp) {
  __shared__ float so[16][260];
  __shared__ float shinv;
  const int bx = blockIdx.x;
  const int b = bx >> 4, tile = bx & 15;
  const int tid = threadIdx.x, lane = tid & 63, w = tid >> 6;
  if (tid == 0) {
    float s = 0.f;
#pragma unroll
    for (int k = 0; k < 16; ++k) s += partial[b * 16 + k];
    shinv = 1.0f / (s * 4294967296.0f);  // fold 2^-32 WHT scaling + 1/norm^2
  }
  const float* pre = Are + ((size_t)b << 16);
  const float* pim = Aim + ((size_t)b << 16);
#pragma unroll
  for (int r = 0; r < 4; ++r) {
    const int ll = w * 4 + r;
    const int mlo = tile * 16 + ll;
    const float4 vr = *reinterpret_cast<const float4*>(pre + mlo * 256 + lane * 4);
    const float4 vi = *reinterpret_cast<const float4*>(pim + mlo * 256 + lane * 4);
    float xr[4] = {vr.x, vr.y, vr.z, vr.w};
    float xi[4] = {vi.x, vi.y, vi.z, vi.w};
    wht256(xr, xi, lane);
    *reinterpret_cast<float4*>(&so[ll][lane * 4]) =
        make_float4(xr[0]*xr[0]+xi[0]*xi[0], xr[1]*xr[1]+xi[1]*xi[1],
                    xr[2]*xr[2]+xi[2]*xi[2], xr[3]*xr[3]+xi[3]*xi[3]);
  }
  __syncthreads();
  const float iv = shinv;
  float* op = outp + ((size_t)b << 16) + tile * 16;
  const int q = tid & 3, l4 = tid >> 2;
#pragma unroll
  for (int it = 0; it < 4; ++it) {
    const int mhi = it * 64 + l4;
    float4 o;
    o.x = so[q*4+0][mhi] * iv; o.y = so[q*4+1][mhi] * iv;
    o.z = so[q*4+2][mhi] * iv; o.w = so[q*4+3][mhi] * iv;
    *reinterpret_cast<float4*>(op + (size_t)mhi * 256 + q * 4) = o;
  }
}

extern "C" void kernel_launch(void* const* d_in, const int* in_sizes, int n_in,
                              void* d_out, int out_size, void* d_ws, size_t ws_size,
                              hipStream_t stream) {
  const float* sre = (const float*)d_in[0];
  const float* sim = (const float*)d_in[1];
  const float* thetas = (const float*)d_in[2];
  const int* cnot = (const int*)d_in[3];
  float* outp = (float*)d_out;
  char* w = (char*)d_ws;
  const size_t PLANE = (size_t)NB * NS * sizeof(float);  // 32 MB
  if (ws_size < 3 * PLANE + 2048 * sizeof(float)) return;  // need ~96 MB scratch
  float* Are = (float*)(w);
  float* Aim = (float*)(w + PLANE);
  float* vre = (float*)(w + 2 * PLANE);
  float* partial = (float*)(w + 3 * PLANE);
  float* vim = outp;  // stage v_im in d_out (fully overwritten by K4)

  dim3 grid(2048), blk(256);
  hipLaunchKernelGGL(k1_whtlo, grid, blk, 0, stream, sre, sim, Are, Aim, partial);
  hipLaunchKernelGGL(k2_whthi_phase, grid, blk, 0, stream, Are, Aim, thetas, vre, vim);
  hipLaunchKernelGGL(k3_gather_whtlo, grid, blk, 0, stream, vre, vim, cnot, Are, Aim);
  hipLaunchKernelGGL(k4_whthi_out, grid, blk, 0, stream, Are, Aim, partial, outp);
}

// Round 2
// 100.509 us; speedup vs baseline: 1.0171x; 1.0171x over previous
//
#include <hip/hip_runtime.h>

#define NB 128
#define NS 65536

// In-wave 256-point Walsh-Hadamard transform (unnormalized).
// Element e = 4*lane + q. Bits 0,1 in registers; bits 2..7 via shfl_xor.
__device__ __forceinline__ void wht256(float (&xr)[4], float (&xi)[4], int lane) {
  {
    float t;
    t = xr[0]; xr[0] = t + xr[1]; xr[1] = t - xr[1];
    t = xr[2]; xr[2] = t + xr[3]; xr[3] = t - xr[3];
    t = xi[0]; xi[0] = t + xi[1]; xi[1] = t - xi[1];
    t = xi[2]; xi[2] = t + xi[3]; xi[3] = t - xi[3];
    t = xr[0]; xr[0] = t + xr[2]; xr[2] = t - xr[2];
    t = xr[1]; xr[1] = t + xr[3]; xr[3] = t - xr[3];
    t = xi[0]; xi[0] = t + xi[2]; xi[2] = t - xi[2];
    t = xi[1]; xi[1] = t + xi[3]; xi[3] = t - xi[3];
  }
#pragma unroll
  for (int m = 1; m <= 32; m <<= 1) {
    const bool up = (lane & m) != 0;
#pragma unroll
    for (int q = 0; q < 4; ++q) {
      float o = __shfl_xor(xr[q], m, 64);
      xr[q] = up ? (o - xr[q]) : (xr[q] + o);
      o = __shfl_xor(xi[q], m, 64);
      xi[q] = up ? (o - xi[q]) : (xi[q] + o);
    }
  }
}

// K0: build separable M^T tables from cnot_p (GF(2)-linear permutation).
// M's column k is p[1<<k]. t_j = M^T e_j assembled bitwise; olo/ohi are the
// XOR-prefix tables over the low/high byte. out[ohi[hi]^olo[lo]] = |u[m]|^2.
__global__ void k0_tables(const int* __restrict__ cnot,
                          int* __restrict__ olo, int* __restrict__ ohi) {
  __shared__ int tj[16];
  const int t = threadIdx.x;  // 256 threads
  if (t < 16) {
    int v = 0;
#pragma unroll
    for (int i = 0; i < 16; ++i) v |= ((cnot[1 << i] >> t) & 1) << i;
    tj[t] = v;
  }
  __syncthreads();
  int lo = 0, hi = 0;
#pragma unroll
  for (int b = 0; b < 8; ++b) {
    if ((t >> b) & 1) { lo ^= tj[b]; hi ^= tj[8 + b]; }
  }
  olo[t] = lo;
  ohi[t] = hi;
}

// K1: WHT along lo byte; write transposed [b][lo][hi]; norm^2 partials.
__global__ __launch_bounds__(256) void k1_whtlo(const float* __restrict__ sre,
                                                const float* __restrict__ sim,
                                                float* __restrict__ Are,
                                                float* __restrict__ Aim,
                                                float* __restrict__ partial) {
  __shared__ float sr[16][260];
  __shared__ float si[16][260];
  __shared__ float red[4];
  const int bx = blockIdx.x;
  const int b = bx >> 4, tile = bx & 15;
  const int tid = threadIdx.x, lane = tid & 63, w = tid >> 6;
  const float* pre = sre + ((size_t)b << 16);
  const float* pim = sim + ((size_t)b << 16);
  float acc = 0.f;
#pragma unroll
  for (int r = 0; r < 4; ++r) {
    const int hl = w * 4 + r;
    const int hi = tile * 16 + hl;
    const float4 vr = *reinterpret_cast<const float4*>(pre + hi * 256 + lane * 4);
    const float4 vi = *reinterpret_cast<const float4*>(pim + hi * 256 + lane * 4);
    float xr[4] = {vr.x, vr.y, vr.z, vr.w};
    float xi[4] = {vi.x, vi.y, vi.z, vi.w};
    acc += xr[0]*xr[0]+xr[1]*xr[1]+xr[2]*xr[2]+xr[3]*xr[3]
         + xi[0]*xi[0]+xi[1]*xi[1]+xi[2]*xi[2]+xi[3]*xi[3];
    wht256(xr, xi, lane);
    *reinterpret_cast<float4*>(&sr[hl][lane * 4]) = make_float4(xr[0], xr[1], xr[2], xr[3]);
    *reinterpret_cast<float4*>(&si[hl][lane * 4]) = make_float4(xi[0], xi[1], xi[2], xi[3]);
  }
#pragma unroll
  for (int m = 32; m >= 1; m >>= 1) acc += __shfl_xor(acc, m, 64);
  if (lane == 0) red[w] = acc;
  __syncthreads();
  if (tid == 0) partial[bx] = red[0] + red[1] + red[2] + red[3];
  float* ore = Are + ((size_t)b << 16) + tile * 16;
  float* oim = Aim + ((size_t)b << 16) + tile * 16;
  const int q = tid & 3, l4 = tid >> 2;
#pragma unroll
  for (int it = 0; it < 4; ++it) {
    const int lo = it * 64 + l4;
    float4 o;
    o.x = sr[q*4+0][lo]; o.y = sr[q*4+1][lo]; o.z = sr[q*4+2][lo]; o.w = sr[q*4+3][lo];
    *reinterpret_cast<float4*>(ore + (size_t)lo * 256 + q * 4) = o;
    o.x = si[q*4+0][lo]; o.y = si[q*4+1][lo]; o.z = si[q*4+2][lo]; o.w = si[q*4+3][lo];
    *reinterpret_cast<float4*>(oim + (size_t)lo * 256 + q * 4) = o;
  }
}

// K2: WHT along hi + separable phase + second WHT along hi (the final H's
// hi-part, applied while data is in registers); write u natural [b][hi][lo].
__global__ __launch_bounds__(256) void k2_whthi2_phase(const float* __restrict__ Are,
                                                       const float* __restrict__ Aim,
                                                       const float* __restrict__ thetas,
                                                       float* __restrict__ ure,
                                                       float* __restrict__ uim) {
  __shared__ float sr[16][260];
  __shared__ float si[16][260];
  __shared__ float2 phh[256];
  __shared__ float2 phl[16];
  __shared__ float th[16];
  const int bx = blockIdx.x;
  const int b = bx >> 4, tile = bx & 15;
  const int tid = threadIdx.x, lane = tid & 63, w = tid >> 6;
  if (tid < 16) th[tid] = thetas[b * 16 + tid];
  __syncthreads();
  {
    float ah = 0.f;
#pragma unroll
    for (int i = 0; i < 8; ++i)
      if ((tid >> (7 - i)) & 1) ah += th[i];
    phh[tid] = make_float2(cosf(0.5f * ah), -sinf(0.5f * ah));
    if (tid < 16) {
      const int lo = tile * 16 + tid;
      float al = 0.f;
#pragma unroll
      for (int i = 0; i < 8; ++i)
        if ((lo >> (7 - i)) & 1) al += th[8 + i];
      phl[tid] = make_float2(cosf(0.5f * al), -sinf(0.5f * al));
    }
  }
  __syncthreads();
  const float* pre = Are + ((size_t)b << 16);
  const float* pim = Aim + ((size_t)b << 16);
#pragma unroll
  for (int r = 0; r < 4; ++r) {
    const int ll = w * 4 + r;
    const int lo = tile * 16 + ll;
    const float4 vr = *reinterpret_cast<const float4*>(pre + lo * 256 + lane * 4);
    const float4 vi = *reinterpret_cast<const float4*>(pim + lo * 256 + lane * 4);
    float xr[4] = {vr.x, vr.y, vr.z, vr.w};
    float xi[4] = {vi.x, vi.y, vi.z, vi.w};
    wht256(xr, xi, lane);
    const float2 pl = phl[ll];
#pragma unroll
    for (int q = 0; q < 4; ++q) {
      const float2 ph = phh[lane * 4 + q];
      const float pr = pl.x * ph.x - pl.y * ph.y;
      const float pi = pl.x * ph.y + pl.y * ph.x;
      const float ur = xr[q], ui = xi[q];
      xr[q] = ur * pr - ui * pi;
      xi[q] = ur * pi + ui * pr;
    }
    wht256(xr, xi, lane);  // second H's hi-part
    *reinterpret_cast<float4*>(&sr[ll][lane * 4]) = make_float4(xr[0], xr[1], xr[2], xr[3]);
    *reinterpret_cast<float4*>(&si[ll][lane * 4]) = make_float4(xi[0], xi[1], xi[2], xi[3]);
  }
  __syncthreads();
  float* ore = ure + ((size_t)b << 16) + tile * 16;
  float* oim = uim + ((size_t)b << 16) + tile * 16;
  const int q = tid & 3, l4 = tid >> 2;
#pragma unroll
  for (int it = 0; it < 4; ++it) {
    const int hi = it * 64 + l4;
    float4 o;
    o.x = sr[q*4+0][hi]; o.y = sr[q*4+1][hi]; o.z = sr[q*4+2][hi]; o.w = sr[q*4+3][hi];
    *reinterpret_cast<float4*>(ore + (size_t)hi * 256 + q * 4) = o;
    o.x = si[q*4+0][hi]; o.y = si[q*4+1][hi]; o.z = si[q*4+2][hi]; o.w = si[q*4+3][hi];
    *reinterpret_cast<float4*>(oim + (size_t)hi * 256 + q * 4) = o;
  }
}

// K3: WHT along lo (final H's lo-part) + |.|^2 scale + permuted scatter write:
// out[ohi[hi] ^ olo[lo]] = |u[hi*256+lo]|^2 * iv.
// blockIdx swizzled so each XCD owns 16 batches (scatter set = 4MB = its L2).
__global__ __launch_bounds__(256) void k3_whtlo_scatter(const float* __restrict__ ure,
                                                        const float* __restrict__ uim,
                                                        const int* __restrict__ olo,
                                                        const int* __restrict__ ohi,
                                                        const float* __restrict__ partial,
                                                        float* __restrict__ outp) {
  __shared__ int slo[256];
  __shared__ float shinv;
  const int bid = blockIdx.x;
  const int x = bid & 7, s = bid >> 3;
  const int b = x * 16 + (s >> 4), tile = s & 15;
  const int tid = threadIdx.x, lane = tid & 63, w = tid >> 6;
  slo[tid] = olo[tid];
  if (tid == 0) {
    float sum = 0.f;
#pragma unroll
    for (int k = 0; k < 16; ++k) sum += partial[b * 16 + k];
    shinv = 1.0f / (sum * 4294967296.0f);  // fold 2^-32 WHT scaling + 1/norm^2
  }
  __syncthreads();
  const float* pre = ure + ((size_t)b << 16);
  const float* pim = uim + ((size_t)b << 16);
  float* ob = outp + ((size_t)b << 16);
  const float iv = shinv;
#pragma unroll
  for (int r = 0; r < 4; ++r) {
    const int hl = w * 4 + r;
    const int hi = tile * 16 + hl;
    const float4 vr = *reinterpret_cast<const float4*>(pre + hi * 256 + lane * 4);
    const float4 vi = *reinterpret_cast<const float4*>(pim + hi * 256 + lane * 4);
    float xr[4] = {vr.x, vr.y, vr.z, vr.w};
    float xi[4] = {vi.x, vi.y, vi.z, vi.w};
    wht256(xr, xi, lane);
    const int oh = ohi[hi];
#pragma unroll
    for (int q = 0; q < 4; ++q) {
      const int k = oh ^ slo[lane * 4 + q];
      ob[k] = (xr[q] * xr[q] + xi[q] * xi[q]) * iv;
    }
  }
}

extern "C" void kernel_launch(void* const* d_in, const int* in_sizes, int n_in,
                              void* d_out, int out_size, void* d_ws, size_t ws_size,
                              hipStream_t stream) {
  const float* sre = (const float*)d_in[0];
  const float* sim = (const float*)d_in[1];
  const float* thetas = (const float*)d_in[2];
  const int* cnot = (const int*)d_in[3];
  float* outp = (float*)d_out;
  char* w = (char*)d_ws;
  const size_t PLANE = (size_t)NB * NS * sizeof(float);  // 32 MB
  if (ws_size < 4 * PLANE + 8192) return;  // need 128 MB scratch + tables
  float* Are = (float*)(w);
  float* Aim = (float*)(w + PLANE);
  float* ure = (float*)(w + 2 * PLANE);
  float* uim = (float*)(w + 3 * PLANE);
  float* partial = (float*)(w + 4 * PLANE);             // 2048 floats
  int* olo = (int*)(w + 4 * PLANE + 2048 * sizeof(float));
  int* ohi = olo + 256;

  dim3 grid(2048), blk(256);
  hipLaunchKernelGGL(k0_tables, dim3(1), blk, 0, stream, cnot, olo, ohi);
  hipLaunchKernelGGL(k1_whtlo, grid, blk, 0, stream, sre, sim, Are, Aim, partial);
  hipLaunchKernelGGL(k2_whthi2_phase, grid, blk, 0, stream, Are, Aim, thetas, ure, uim);
  hipLaunchKernelGGL(k3_whtlo_scatter, grid, blk, 0, stream, ure, uim, olo, ohi, partial, outp);
}

// Round 4
// 79.474 us; speedup vs baseline: 1.2863x; 1.2647x over previous
//
#include <hip/hip_runtime.h>

#define NB 128
#define NS 65536

// ---- VALU-pipe cross-lane helpers -----------------------------------------
template <int CTRL>
__device__ __forceinline__ float dppqp(float x) {
  // DPP quad_perm move (VALU pipe, all lanes active)
  return __int_as_float(__builtin_amdgcn_update_dpp(
      0, __float_as_int(x), CTRL, 0xF, 0xF, false));
}
template <int OFF>
__device__ __forceinline__ float dswz(float x) {
  return __int_as_float(__builtin_amdgcn_ds_swizzle(__float_as_int(x), OFF));
}

// In-wave 256-point Walsh-Hadamard transform (unnormalized).
// Element e = 4*lane + q. Bits 0,1 in registers; lane bits:
//  xor1,xor2 via DPP quad_perm; xor4,xor8 via ds_swizzle;
//  xor16,xor32 via v_permlane16/32_swap (VALU) when available.
__device__ __forceinline__ void wht256(float (&xr)[4], float (&xi)[4], int lane) {
  {
    float t;
    t = xr[0]; xr[0] = t + xr[1]; xr[1] = t - xr[1];
    t = xr[2]; xr[2] = t + xr[3]; xr[3] = t - xr[3];
    t = xi[0]; xi[0] = t + xi[1]; xi[1] = t - xi[1];
    t = xi[2]; xi[2] = t + xi[3]; xi[3] = t - xi[3];
    t = xr[0]; xr[0] = t + xr[2]; xr[2] = t - xr[2];
    t = xr[1]; xr[1] = t + xr[3]; xr[3] = t - xr[3];
    t = xi[0]; xi[0] = t + xi[2]; xi[2] = t - xi[2];
    t = xi[1]; xi[1] = t + xi[3]; xi[3] = t - xi[3];
  }
  const float s1  = (lane & 1)  ? -1.f : 1.f;
  const float s2  = (lane & 2)  ? -1.f : 1.f;
  const float s4  = (lane & 4)  ? -1.f : 1.f;
  const float s8  = (lane & 8)  ? -1.f : 1.f;
  const float s16 = (lane & 16) ? -1.f : 1.f;
  const float s32 = (lane & 32) ? -1.f : 1.f;
  // lane-xor1: quad_perm [1,0,3,2] = 0xB1
#pragma unroll
  for (int q = 0; q < 4; ++q) {
    xr[q] = fmaf(s1, xr[q], dppqp<0xB1>(xr[q]));
    xi[q] = fmaf(s1, xi[q], dppqp<0xB1>(xi[q]));
  }
  // lane-xor2: quad_perm [2,3,0,1] = 0x4E
#pragma unroll
  for (int q = 0; q < 4; ++q) {
    xr[q] = fmaf(s2, xr[q], dppqp<0x4E>(xr[q]));
    xi[q] = fmaf(s2, xi[q], dppqp<0x4E>(xi[q]));
  }
  // lane-xor4: ds_swizzle xor-mask 4
#pragma unroll
  for (int q = 0; q < 4; ++q) {
    xr[q] = fmaf(s4, xr[q], dswz<0x101F>(xr[q]));
    xi[q] = fmaf(s4, xi[q], dswz<0x101F>(xi[q]));
  }
  // lane-xor8: ds_swizzle xor-mask 8
#pragma unroll
  for (int q = 0; q < 4; ++q) {
    xr[q] = fmaf(s8, xr[q], dswz<0x201F>(xr[q]));
    xi[q] = fmaf(s8, xi[q], dswz<0x201F>(xi[q]));
  }
  // lane-xor16
#if __has_builtin(__builtin_amdgcn_permlane16_swap)
#pragma unroll
  for (int q = 0; q < 4; ++q) {
    {
      auto r = __builtin_amdgcn_permlane16_swap(__float_as_uint(xr[q]),
                                                __float_as_uint(xr[q]), false, false);
      xr[q] = fmaf(s16, __uint_as_float(r[1]), __uint_as_float(r[0]));
    }
    {
      auto r = __builtin_amdgcn_permlane16_swap(__float_as_uint(xi[q]),
                                                __float_as_uint(xi[q]), false, false);
      xi[q] = fmaf(s16, __uint_as_float(r[1]), __uint_as_float(r[0]));
    }
  }
#else
#pragma unroll
  for (int q = 0; q < 4; ++q) {
    float o = __shfl_xor(xr[q], 16, 64);
    xr[q] = fmaf(s16, xr[q], o);
    o = __shfl_xor(xi[q], 16, 64);
    xi[q] = fmaf(s16, xi[q], o);
  }
#endif
  // lane-xor32
#if __has_builtin(__builtin_amdgcn_permlane32_swap)
#pragma unroll
  for (int q = 0; q < 4; ++q) {
    {
      auto r = __builtin_amdgcn_permlane32_swap(__float_as_uint(xr[q]),
                                                __float_as_uint(xr[q]), false, false);
      xr[q] = fmaf(s32, __uint_as_float(r[1]), __uint_as_float(r[0]));
    }
    {
      auto r = __builtin_amdgcn_permlane32_swap(__float_as_uint(xi[q]),
                                                __float_as_uint(xi[q]), false, false);
      xi[q] = fmaf(s32, __uint_as_float(r[1]), __uint_as_float(r[0]));
    }
  }
#else
#pragma unroll
  for (int q = 0; q < 4; ++q) {
    float o = __shfl_xor(xr[q], 32, 64);
    xr[q] = fmaf(s32, xr[q], o);
    o = __shfl_xor(xi[q], 32, 64);
    xi[q] = fmaf(s32, xi[q], o);
  }
#endif
}

// K1: WHT along lo byte; write transposed [b][lo][hi]; norm^2 partials.
__global__ __launch_bounds__(256) void k1_whtlo(const float* __restrict__ sre,
                                                const float* __restrict__ sim,
                                                float* __restrict__ Are,
                                                float* __restrict__ Aim,
                                                float* __restrict__ partial) {
  __shared__ float sr[16][260];
  __shared__ float si[16][260];
  __shared__ float red[4];
  const int bx = blockIdx.x;
  const int b = bx >> 4, tile = bx & 15;
  const int tid = threadIdx.x, lane = tid & 63, w = tid >> 6;
  const float* pre = sre + ((size_t)b << 16);
  const float* pim = sim + ((size_t)b << 16);
  float acc = 0.f;
#pragma unroll
  for (int r = 0; r < 4; ++r) {
    const int hl = w * 4 + r;
    const int hi = tile * 16 + hl;
    const float4 vr = *reinterpret_cast<const float4*>(pre + hi * 256 + lane * 4);
    const float4 vi = *reinterpret_cast<const float4*>(pim + hi * 256 + lane * 4);
    float xr[4] = {vr.x, vr.y, vr.z, vr.w};
    float xi[4] = {vi.x, vi.y, vi.z, vi.w};
    acc += xr[0]*xr[0]+xr[1]*xr[1]+xr[2]*xr[2]+xr[3]*xr[3]
         + xi[0]*xi[0]+xi[1]*xi[1]+xi[2]*xi[2]+xi[3]*xi[3];
    wht256(xr, xi, lane);
    *reinterpret_cast<float4*>(&sr[hl][lane * 4]) = make_float4(xr[0], xr[1], xr[2], xr[3]);
    *reinterpret_cast<float4*>(&si[hl][lane * 4]) = make_float4(xi[0], xi[1], xi[2], xi[3]);
  }
#pragma unroll
  for (int m = 32; m >= 1; m >>= 1) acc += __shfl_xor(acc, m, 64);
  if (lane == 0) red[w] = acc;
  __syncthreads();
  if (tid == 0) partial[bx] = red[0] + red[1] + red[2] + red[3];
  float* ore = Are + ((size_t)b << 16) + tile * 16;
  float* oim = Aim + ((size_t)b << 16) + tile * 16;
  const int q = tid & 3, l4 = tid >> 2;
#pragma unroll
  for (int it = 0; it < 4; ++it) {
    const int lo = it * 64 + l4;
    float4 o;
    o.x = sr[q*4+0][lo]; o.y = sr[q*4+1][lo]; o.z = sr[q*4+2][lo]; o.w = sr[q*4+3][lo];
    *reinterpret_cast<float4*>(ore + (size_t)lo * 256 + q * 4) = o;
    o.x = si[q*4+0][lo]; o.y = si[q*4+1][lo]; o.z = si[q*4+2][lo]; o.w = si[q*4+3][lo];
    *reinterpret_cast<float4*>(oim + (size_t)lo * 256 + q * 4) = o;
  }
}

// K2: WHT along hi + separable phase + second WHT along hi (the final H's
// hi-part, applied while data is in registers); write u natural [b][hi][lo].
__global__ __launch_bounds__(256) void k2_whthi2_phase(const float* __restrict__ Are,
                                                       const float* __restrict__ Aim,
                                                       const float* __restrict__ thetas,
                                                       float* __restrict__ ure,
                                                       float* __restrict__ uim) {
  __shared__ float sr[16][260];
  __shared__ float si[16][260];
  __shared__ float2 phh[256];
  __shared__ float2 phl[16];
  __shared__ float th[16];
  const int bx = blockIdx.x;
  const int b = bx >> 4, tile = bx & 15;
  const int tid = threadIdx.x, lane = tid & 63, w = tid >> 6;
  if (tid < 16) th[tid] = thetas[b * 16 + tid];
  __syncthreads();
  {
    float ah = 0.f;
#pragma unroll
    for (int i = 0; i < 8; ++i)
      if ((tid >> (7 - i)) & 1) ah += th[i];
    phh[tid] = make_float2(cosf(0.5f * ah), -sinf(0.5f * ah));
    if (tid < 16) {
      const int lo = tile * 16 + tid;
      float al = 0.f;
#pragma unroll
      for (int i = 0; i < 8; ++i)
        if ((lo >> (7 - i)) & 1) al += th[8 + i];
      phl[tid] = make_float2(cosf(0.5f * al), -sinf(0.5f * al));
    }
  }
  __syncthreads();
  const float* pre = Are + ((size_t)b << 16);
  const float* pim = Aim + ((size_t)b << 16);
#pragma unroll
  for (int r = 0; r < 4; ++r) {
    const int ll = w * 4 + r;
    const int lo = tile * 16 + ll;
    const float4 vr = *reinterpret_cast<const float4*>(pre + lo * 256 + lane * 4);
    const float4 vi = *reinterpret_cast<const float4*>(pim + lo * 256 + lane * 4);
    float xr[4] = {vr.x, vr.y, vr.z, vr.w};
    float xi[4] = {vi.x, vi.y, vi.z, vi.w};
    wht256(xr, xi, lane);
    const float2 pl = phl[ll];
#pragma unroll
    for (int q = 0; q < 4; ++q) {
      const float2 ph = phh[lane * 4 + q];
      const float pr = pl.x * ph.x - pl.y * ph.y;
      const float pi = pl.x * ph.y + pl.y * ph.x;
      const float ur = xr[q], ui = xi[q];
      xr[q] = ur * pr - ui * pi;
      xi[q] = ur * pi + ui * pr;
    }
    wht256(xr, xi, lane);  // second H's hi-part
    *reinterpret_cast<float4*>(&sr[ll][lane * 4]) = make_float4(xr[0], xr[1], xr[2], xr[3]);
    *reinterpret_cast<float4*>(&si[ll][lane * 4]) = make_float4(xi[0], xi[1], xi[2], xi[3]);
  }
  __syncthreads();
  float* ore = ure + ((size_t)b << 16) + tile * 16;
  float* oim = uim + ((size_t)b << 16) + tile * 16;
  const int q = tid & 3, l4 = tid >> 2;
#pragma unroll
  for (int it = 0; it < 4; ++it) {
    const int hi = it * 64 + l4;
    float4 o;
    o.x = sr[q*4+0][hi]; o.y = sr[q*4+1][hi]; o.z = sr[q*4+2][hi]; o.w = sr[q*4+3][hi];
    *reinterpret_cast<float4*>(ore + (size_t)hi * 256 + q * 4) = o;
    o.x = si[q*4+0][hi]; o.y = si[q*4+1][hi]; o.z = si[q*4+2][hi]; o.w = si[q*4+3][hi];
    *reinterpret_cast<float4*>(oim + (size_t)hi * 256 + q * 4) = o;
  }
}

// K3: WHT along lo (final H's lo-part) + |.|^2 scale + permuted scatter write:
// out[shi[hl] ^ slo[lo]] = |u[hi*256+lo]|^2 * iv.  M^T tables built in-block
// from cnot_p (GF(2)-linear permutation; column k of M is p[1<<k]).
// blockIdx swizzled so each XCD owns 16 batches (scatter set = 4MB = its L2).
__global__ __launch_bounds__(256) void k3_whtlo_scatter(const float* __restrict__ ure,
                                                        const float* __restrict__ uim,
                                                        const int* __restrict__ cnot,
                                                        const float* __restrict__ partial,
                                                        float* __restrict__ outp) {
  __shared__ int tj[16];
  __shared__ int slo[256];
  __shared__ int shi[16];
  __shared__ float shinv;
  const int bid = blockIdx.x;
  const int x = bid & 7, s = bid >> 3;
  const int b = x * 16 + (s >> 4), tile = s & 15;
  const int tid = threadIdx.x, lane = tid & 63, w = tid >> 6;
  if (tid < 16) {
    int v = 0;
#pragma unroll
    for (int i = 0; i < 16; ++i) v |= ((cnot[1 << i] >> tid) & 1) << i;
    tj[tid] = v;
  }
  if (tid == 0) {
    float sum = 0.f;
#pragma unroll
    for (int k = 0; k < 16; ++k) sum += partial[b * 16 + k];
    shinv = 1.0f / (sum * 4294967296.0f);  // fold 2^-32 WHT scaling + 1/norm^2
  }
  __syncthreads();
  {
    int lo = 0;
#pragma unroll
    for (int bb = 0; bb < 8; ++bb)
      if ((tid >> bb) & 1) lo ^= tj[bb];
    slo[tid] = lo;
  }
  if (tid < 16) {
    const int h = tile * 16 + tid;
    int v = 0;
#pragma unroll
    for (int bb = 0; bb < 8; ++bb)
      if ((h >> bb) & 1) v ^= tj[8 + bb];
    shi[tid] = v;
  }
  __syncthreads();
  const float* pre = ure + ((size_t)b << 16);
  const float* pim = uim + ((size_t)b << 16);
  float* ob = outp + ((size_t)b << 16);
  const float iv = shinv;
#pragma unroll
  for (int r = 0; r < 4; ++r) {
    const int hl = w * 4 + r;
    const int hi = tile * 16 + hl;
    const float4 vr = *reinterpret_cast<const float4*>(pre + hi * 256 + lane * 4);
    const float4 vi = *reinterpret_cast<const float4*>(pim + hi * 256 + lane * 4);
    float xr[4] = {vr.x, vr.y, vr.z, vr.w};
    float xi[4] = {vi.x, vi.y, vi.z, vi.w};
    wht256(xr, xi, lane);
    const int oh = shi[hl];
#pragma unroll
    for (int q = 0; q < 4; ++q) {
      const int k = oh ^ slo[lane * 4 + q];
      ob[k] = (xr[q] * xr[q] + xi[q] * xi[q]) * iv;
    }
  }
}

extern "C" void kernel_launch(void* const* d_in, const int* in_sizes, int n_in,
                              void* d_out, int out_size, void* d_ws, size_t ws_size,
                              hipStream_t stream) {
  const float* sre = (const float*)d_in[0];
  const float* sim = (const float*)d_in[1];
  const float* thetas = (const float*)d_in[2];
  const int* cnot = (const int*)d_in[3];
  float* outp = (float*)d_out;
  char* w = (char*)d_ws;
  const size_t PLANE = (size_t)NB * NS * sizeof(float);  // 32 MB
  if (ws_size < 4 * PLANE + 8192) return;  // need 128 MB scratch + partials
  float* Are = (float*)(w);
  float* Aim = (float*)(w + PLANE);
  float* ure = (float*)(w + 2 * PLANE);
  float* uim = (float*)(w + 3 * PLANE);
  float* partial = (float*)(w + 4 * PLANE);  // 2048 floats

  dim3 grid(2048), blk(256);
  hipLaunchKernelGGL(k1_whtlo, grid, blk, 0, stream, sre, sim, Are, Aim, partial);
  hipLaunchKernelGGL(k2_whthi2_phase, grid, blk, 0, stream, Are, Aim, thetas, ure, uim);
  hipLaunchKernelGGL(k3_whtlo_scatter, grid, blk, 0, stream, ure, uim, cnot, partial, outp);
}

// Round 5
// 76.460 us; speedup vs baseline: 1.3371x; 1.0394x over previous
//
#include <hip/hip_runtime.h>

#define NB 128
#define NS 65536
#define PITCH 524  // floats per LDS row: 16B-aligned rows, 2-way-max col reads

// ---- VALU-pipe cross-lane helpers -----------------------------------------
template <int CTRL>
__device__ __forceinline__ float dppqp(float x) {
  return __int_as_float(__builtin_amdgcn_update_dpp(
      0, __float_as_int(x), CTRL, 0xF, 0xF, false));
}
template <int OFF>
__device__ __forceinline__ float dswz(float x) {
  return __int_as_float(__builtin_amdgcn_ds_swizzle(__float_as_int(x), OFF));
}

// In-wave 256-point Walsh-Hadamard transform (unnormalized).
// Element e = 4*lane + q. Bits 0,1 in registers; lane bits:
//  xor1,xor2 via DPP quad_perm; xor4,xor8 via ds_swizzle;
//  xor16,xor32 via v_permlane16/32_swap (VALU).
__device__ __forceinline__ void wht256(float (&xr)[4], float (&xi)[4], int lane) {
  {
    float t;
    t = xr[0]; xr[0] = t + xr[1]; xr[1] = t - xr[1];
    t = xr[2]; xr[2] = t + xr[3]; xr[3] = t - xr[3];
    t = xi[0]; xi[0] = t + xi[1]; xi[1] = t - xi[1];
    t = xi[2]; xi[2] = t + xi[3]; xi[3] = t - xi[3];
    t = xr[0]; xr[0] = t + xr[2]; xr[2] = t - xr[2];
    t = xr[1]; xr[1] = t + xr[3]; xr[3] = t - xr[3];
    t = xi[0]; xi[0] = t + xi[2]; xi[2] = t - xi[2];
    t = xi[1]; xi[1] = t + xi[3]; xi[3] = t - xi[3];
  }
  const float s1  = (lane & 1)  ? -1.f : 1.f;
  const float s2  = (lane & 2)  ? -1.f : 1.f;
  const float s4  = (lane & 4)  ? -1.f : 1.f;
  const float s8  = (lane & 8)  ? -1.f : 1.f;
  const float s16 = (lane & 16) ? -1.f : 1.f;
  const float s32 = (lane & 32) ? -1.f : 1.f;
#pragma unroll
  for (int q = 0; q < 4; ++q) {
    xr[q] = fmaf(s1, xr[q], dppqp<0xB1>(xr[q]));
    xi[q] = fmaf(s1, xi[q], dppqp<0xB1>(xi[q]));
  }
#pragma unroll
  for (int q = 0; q < 4; ++q) {
    xr[q] = fmaf(s2, xr[q], dppqp<0x4E>(xr[q]));
    xi[q] = fmaf(s2, xi[q], dppqp<0x4E>(xi[q]));
  }
#pragma unroll
  for (int q = 0; q < 4; ++q) {
    xr[q] = fmaf(s4, xr[q], dswz<0x101F>(xr[q]));
    xi[q] = fmaf(s4, xi[q], dswz<0x101F>(xi[q]));
  }
#pragma unroll
  for (int q = 0; q < 4; ++q) {
    xr[q] = fmaf(s8, xr[q], dswz<0x201F>(xr[q]));
    xi[q] = fmaf(s8, xi[q], dswz<0x201F>(xi[q]));
  }
#pragma unroll
  for (int q = 0; q < 4; ++q) {
    {
      auto r = __builtin_amdgcn_permlane16_swap(__float_as_uint(xr[q]),
                                                __float_as_uint(xr[q]), false, false);
      xr[q] = fmaf(s16, __uint_as_float(r[1]), __uint_as_float(r[0]));
    }
    {
      auto r = __builtin_amdgcn_permlane16_swap(__float_as_uint(xi[q]),
                                                __float_as_uint(xi[q]), false, false);
      xi[q] = fmaf(s16, __uint_as_float(r[1]), __uint_as_float(r[0]));
    }
  }
#pragma unroll
  for (int q = 0; q < 4; ++q) {
    {
      auto r = __builtin_amdgcn_permlane32_swap(__float_as_uint(xr[q]),
                                                __float_as_uint(xr[q]), false, false);
      xr[q] = fmaf(s32, __uint_as_float(r[1]), __uint_as_float(r[0]));
    }
    {
      auto r = __builtin_amdgcn_permlane32_swap(__float_as_uint(xi[q]),
                                                __float_as_uint(xi[q]), false, false);
      xi[q] = fmaf(s32, __uint_as_float(r[1]), __uint_as_float(r[0]));
    }
  }
}

// K1: WHT along lo byte; write complex-interleaved transposed AC[b][lo][hi];
// norm^2 partials. 512 threads (8 waves x 2 rows), single [16][524] LDS tile.
__global__ __launch_bounds__(512, 8) void k1_whtlo(const float* __restrict__ sre,
                                                   const float* __restrict__ sim,
                                                   float* __restrict__ AC,
                                                   float* __restrict__ partial) {
  __shared__ float sc[16][PITCH];
  __shared__ float red[8];
  const int bx = blockIdx.x;
  const int b = bx >> 4, tile = bx & 15;
  const int tid = threadIdx.x, lane = tid & 63, w = tid >> 6;
  const float* pre = sre + ((size_t)b << 16);
  const float* pim = sim + ((size_t)b << 16);
  float acc = 0.f;
#pragma unroll
  for (int r = 0; r < 2; ++r) {
    const int hl = w * 2 + r;
    const int hi = tile * 16 + hl;
    const float4 vr = *reinterpret_cast<const float4*>(pre + hi * 256 + lane * 4);
    const float4 vi = *reinterpret_cast<const float4*>(pim + hi * 256 + lane * 4);
    float xr[4] = {vr.x, vr.y, vr.z, vr.w};
    float xi[4] = {vi.x, vi.y, vi.z, vi.w};
    acc += xr[0]*xr[0]+xr[1]*xr[1]+xr[2]*xr[2]+xr[3]*xr[3]
         + xi[0]*xi[0]+xi[1]*xi[1]+xi[2]*xi[2]+xi[3]*xi[3];
    wht256(xr, xi, lane);
    // interleave: word 2e+0 = re(e), 2e+1 = im(e); e = lane*4+q
    *reinterpret_cast<float4*>(&sc[hl][lane * 8]) =
        make_float4(xr[0], xi[0], xr[1], xi[1]);
    *reinterpret_cast<float4*>(&sc[hl][lane * 8 + 4]) =
        make_float4(xr[2], xi[2], xr[3], xi[3]);
  }
#pragma unroll
  for (int m = 32; m >= 1; m >>= 1) acc += __shfl_xor(acc, m, 64);
  if (lane == 0) red[w] = acc;
  __syncthreads();
  if (tid == 0) {
    float s = 0.f;
#pragma unroll
    for (int k = 0; k < 8; ++k) s += red[k];
    partial[bx] = s;
  }
  // epilogue: column-read -> full 128B chunks of AC[b][lo][hi] (float2 pairs)
  float* ob = AC + ((size_t)b << 17) + tile * 32;
  const int q = tid & 7, l4 = tid >> 3;
#pragma unroll
  for (int it = 0; it < 4; ++it) {
    const int lo = it * 64 + l4;
    const float2 a = *reinterpret_cast<const float2*>(&sc[2 * q][2 * lo]);
    const float2 c = *reinterpret_cast<const float2*>(&sc[2 * q + 1][2 * lo]);
    *reinterpret_cast<float4*>(ob + (size_t)lo * 512 + q * 4) =
        make_float4(a.x, a.y, c.x, c.y);
  }
}

// K2: WHT along hi + separable phase + second WHT along hi; complex-interleaved
// in AC[b][lo][hi], out UC[b][hi][lo]. 512 threads, single LDS tile.
__global__ __launch_bounds__(512, 8) void k2_whthi2_phase(const float* __restrict__ AC,
                                                          const float* __restrict__ thetas,
                                                          float* __restrict__ UC) {
  __shared__ float sc[16][PITCH];
  __shared__ float2 phh[256];
  __shared__ float2 phl[16];
  __shared__ float th[16];
  const int bx = blockIdx.x;
  const int b = bx >> 4, tile = bx & 15;
  const int tid = threadIdx.x, lane = tid & 63, w = tid >> 6;
  if (tid < 16) th[tid] = thetas[b * 16 + tid];
  __syncthreads();
  if (tid < 256) {
    float ah = 0.f;
#pragma unroll
    for (int i = 0; i < 8; ++i)
      if ((tid >> (7 - i)) & 1) ah += th[i];
    phh[tid] = make_float2(cosf(0.5f * ah), -sinf(0.5f * ah));
    if (tid < 16) {
      const int lo = tile * 16 + tid;
      float al = 0.f;
#pragma unroll
      for (int i = 0; i < 8; ++i)
        if ((lo >> (7 - i)) & 1) al += th[8 + i];
      phl[tid] = make_float2(cosf(0.5f * al), -sinf(0.5f * al));
    }
  }
  __syncthreads();
  const float* pb = AC + ((size_t)b << 17);
#pragma unroll
  for (int r = 0; r < 2; ++r) {
    const int ll = w * 2 + r;
    const int lo = tile * 16 + ll;
    const float4 va = *reinterpret_cast<const float4*>(pb + (size_t)lo * 512 + lane * 8);
    const float4 vb = *reinterpret_cast<const float4*>(pb + (size_t)lo * 512 + lane * 8 + 4);
    float xr[4] = {va.x, va.z, vb.x, vb.z};
    float xi[4] = {va.y, va.w, vb.y, vb.w};
    wht256(xr, xi, lane);
    const float2 pl = phl[ll];
#pragma unroll
    for (int q = 0; q < 4; ++q) {
      const float2 ph = phh[lane * 4 + q];
      const float pr = pl.x * ph.x - pl.y * ph.y;
      const float pi = pl.x * ph.y + pl.y * ph.x;
      const float ur = xr[q], ui = xi[q];
      xr[q] = ur * pr - ui * pi;
      xi[q] = ur * pi + ui * pr;
    }
    wht256(xr, xi, lane);  // second H's hi-part
    *reinterpret_cast<float4*>(&sc[ll][lane * 8]) =
        make_float4(xr[0], xi[0], xr[1], xi[1]);
    *reinterpret_cast<float4*>(&sc[ll][lane * 8 + 4]) =
        make_float4(xr[2], xi[2], xr[3], xi[3]);
  }
  __syncthreads();
  float* ob = UC + ((size_t)b << 17) + tile * 32;
  const int q = tid & 7, l4 = tid >> 3;
#pragma unroll
  for (int it = 0; it < 4; ++it) {
    const int hi = it * 64 + l4;
    const float2 a = *reinterpret_cast<const float2*>(&sc[2 * q][2 * hi]);
    const float2 c = *reinterpret_cast<const float2*>(&sc[2 * q + 1][2 * hi]);
    *reinterpret_cast<float4*>(ob + (size_t)hi * 512 + q * 4) =
        make_float4(a.x, a.y, c.x, c.y);
  }
}

// K3: WHT along lo (final H's lo-part) + |.|^2 scale + permuted scatter write:
// out[shi[hl] ^ slo[lo]] = |u|^2 * iv.  M^T tables built in-block from cnot_p
// (GF(2)-linear permutation; column k of M is p[1<<k]).
// blockIdx swizzled so each XCD owns 16 batches (scatter set = 4MB = its L2).
__global__ __launch_bounds__(256, 8) void k3_whtlo_scatter(const float* __restrict__ UC,
                                                           const int* __restrict__ cnot,
                                                           const float* __restrict__ partial,
                                                           float* __restrict__ outp) {
  __shared__ int tj[16];
  __shared__ int slo[256];
  __shared__ int shi[16];
  __shared__ float shinv;
  const int bid = blockIdx.x;
  const int x = bid & 7, s = bid >> 3;
  const int b = x * 16 + (s >> 4), tile = s & 15;
  const int tid = threadIdx.x, lane = tid & 63, w = tid >> 6;
  if (tid < 16) {
    int v = 0;
#pragma unroll
    for (int i = 0; i < 16; ++i) v |= ((cnot[1 << i] >> tid) & 1) << i;
    tj[tid] = v;
  }
  if (tid == 0) {
    float sum = 0.f;
#pragma unroll
    for (int k = 0; k < 16; ++k) sum += partial[b * 16 + k];
    shinv = 1.0f / (sum * 4294967296.0f);  // fold 2^-32 WHT scaling + 1/norm^2
  }
  __syncthreads();
  {
    int lo = 0;
#pragma unroll
    for (int bb = 0; bb < 8; ++bb)
      if ((tid >> bb) & 1) lo ^= tj[bb];
    slo[tid] = lo;
  }
  if (tid < 16) {
    const int h = tile * 16 + tid;
    int v = 0;
#pragma unroll
    for (int bb = 0; bb < 8; ++bb)
      if ((h >> bb) & 1) v ^= tj[8 + bb];
    shi[tid] = v;
  }
  __syncthreads();
  const float* pb = UC + ((size_t)b << 17);
  float* ob = outp + ((size_t)b << 16);
  const float iv = shinv;
#pragma unroll
  for (int r = 0; r < 4; ++r) {
    const int hl = w * 4 + r;
    const int hi = tile * 16 + hl;
    const float4 va = *reinterpret_cast<const float4*>(pb + (size_t)hi * 512 + lane * 8);
    const float4 vb = *reinterpret_cast<const float4*>(pb + (size_t)hi * 512 + lane * 8 + 4);
    float xr[4] = {va.x, va.z, vb.x, vb.z};
    float xi[4] = {va.y, va.w, vb.y, vb.w};
    wht256(xr, xi, lane);
    const int oh = shi[hl];
#pragma unroll
    for (int q = 0; q < 4; ++q) {
      const int k = oh ^ slo[lane * 4 + q];
      ob[k] = (xr[q] * xr[q] + xi[q] * xi[q]) * iv;
    }
  }
}

extern "C" void kernel_launch(void* const* d_in, const int* in_sizes, int n_in,
                              void* d_out, int out_size, void* d_ws, size_t ws_size,
                              hipStream_t stream) {
  const float* sre = (const float*)d_in[0];
  const float* sim = (const float*)d_in[1];
  const float* thetas = (const float*)d_in[2];
  const int* cnot = (const int*)d_in[3];
  float* outp = (float*)d_out;
  char* w = (char*)d_ws;
  const size_t CPLANE = (size_t)NB * NS * 2 * sizeof(float);  // 64 MB complex
  if (ws_size < 2 * CPLANE + 8192) return;  // need 128 MB scratch + partials
  float* AC = (float*)(w);
  float* UC = (float*)(w + CPLANE);
  float* partial = (float*)(w + 2 * CPLANE);  // 2048 floats

  hipLaunchKernelGGL(k1_whtlo, dim3(2048), dim3(512), 0, stream, sre, sim, AC, partial);
  hipLaunchKernelGGL(k2_whthi2_phase, dim3(2048), dim3(512), 0, stream, AC, thetas, UC);
  hipLaunchKernelGGL(k3_whtlo_scatter, dim3(2048), dim3(256), 0, stream, UC, cnot, partial, outp);
}